// Round 8
// baseline (3624.307 us; speedup 1.0000x reference)
//
#include <hip/hip_runtime.h>
#include <math.h>

// Problem: B=256, T=256, D=H=512, O=256, L=3 (cell0 + 2 shared middle cells)
#define kT 256
#define kEPS 1e-5f
#define NBB 96     // 3 groups x 32 persistent blocks (cell0 | cell1 | cell2)
#define BT 1024    // 16 waves -> 4 waves/SIMD on each CU
#define SSTEP 8    // timesteps per grid-barrier tick (amortize barrier cost)
#define NT (kT / SSTEP)   // 32 ticks of work

typedef __attribute__((ext_vector_type(8))) _Float16 half8;  // 8 fp16 (4 VGPRs)
typedef __attribute__((ext_vector_type(4))) float f32x4;

// barrier: 4 spread counters per phase, 64B apart; phase-indexed (memset at launch)
#define BSLOT(p, j) (((p)*4 + (j)) * 16)
#define BARBYTES (260 * 4 * 64)

// pack v as {hi=fp16(v)} | {lo=fp16(v-hi)}<<16 : 22-bit effective mantissa in 4B
__device__ __forceinline__ unsigned packhl(float f) {
    _Float16 hi = (_Float16)f;
    _Float16 lo = (_Float16)(f - (float)hi);
    unsigned short uh, ul;
    __builtin_memcpy(&uh, &hi, 2);
    __builtin_memcpy(&ul, &lo, 2);
    return (unsigned)uh | ((unsigned)ul << 16);
}

__device__ __forceinline__ float unpackhl(unsigned wd) {
    unsigned short uh = (unsigned short)wd, ul = (unsigned short)(wd >> 16);
    _Float16 hi, lo;
    __builtin_memcpy(&hi, &uh, 2);
    __builtin_memcpy(&lo, &ul, 2);
    return (float)hi + (float)lo;
}

// split 8 packed words (two uint4) into hi/lo half8 fragments (8 v_perm_b32)
__device__ __forceinline__ void split32(uint4 A, uint4 B, half8& hi, half8& lo) {
    unsigned hh[4], ll[4];
    hh[0] = __builtin_amdgcn_perm(A.y, A.x, 0x05040100u);
    ll[0] = __builtin_amdgcn_perm(A.y, A.x, 0x07060302u);
    hh[1] = __builtin_amdgcn_perm(A.w, A.z, 0x05040100u);
    ll[1] = __builtin_amdgcn_perm(A.w, A.z, 0x07060302u);
    hh[2] = __builtin_amdgcn_perm(B.y, B.x, 0x05040100u);
    ll[2] = __builtin_amdgcn_perm(B.y, B.x, 0x07060302u);
    hh[3] = __builtin_amdgcn_perm(B.w, B.z, 0x05040100u);
    ll[3] = __builtin_amdgcn_perm(B.w, B.z, 0x07060302u);
    __builtin_memcpy(&hi, hh, 16);
    __builtin_memcpy(&lo, ll, 16);
}

// ============================ kernel 1: pack W0 ============================
__global__ __launch_bounds__(256) void w0pack(const float* __restrict__ W0,
                                              unsigned* __restrict__ W0p) {
    const int i4 = (blockIdx.x * 256 + threadIdx.x) * 4;   // 262144 words total
    float4 v = *(const float4*)(W0 + i4);
    uint4 pw;
    pw.x = packhl(v.x); pw.y = packhl(v.y); pw.z = packhl(v.z); pw.w = packhl(v.w);
    *(uint4*)(W0p + i4) = pw;
}

// ================= kernel 2: z0 = x @ W0^T, packed, IN PLACE over x ========
#define ZROWS 32
#define XSTR 516   // padded word stride: 2-way bank aliasing only (free)
__global__ __launch_bounds__(1024, 4) void zgemm(float* __restrict__ x,
                                                 const unsigned* __restrict__ W0p) {
    __shared__ unsigned xs[ZROWS * XSTR];
    const int tid = threadIdx.x;
    const long long r0 = (long long)blockIdx.x * ZROWS;

    {   // stage 32 rows x 512 floats -> packed words in LDS
        const int row = tid >> 5;
        const int k0 = (tid & 31) * 16;
        const float* src = x + (r0 + row) * 512 + k0;
        unsigned* dst = xs + row * XSTR + k0;
#pragma unroll
        for (int i = 0; i < 4; ++i) {
            float4 v = *(const float4*)(src + i * 4);
            uint4 pw;
            pw.x = packhl(v.x); pw.y = packhl(v.y); pw.z = packhl(v.z); pw.w = packhl(v.w);
            *(uint4*)(dst + i * 4) = pw;
        }
    }
    __syncthreads();

    const int w = tid >> 6, lane = tid & 63, q = lane >> 4, c = lane & 15;
    const int mt0 = w * 2;
    f32x4 acc[2][2] = {};
#pragma unroll
    for (int ks = 0; ks < 16; ++ks) {
        half8 ahi[2], alo[2], bhi[2], blo[2];
#pragma unroll
        for (int m = 0; m < 2; ++m) {
            const unsigned* ap = W0p + ((mt0 + m) * 16 + c) * 512 + ks * 32 + q * 8;
            split32(*(const uint4*)ap, *(const uint4*)(ap + 4), ahi[m], alo[m]);
        }
#pragma unroll
        for (int s = 0; s < 2; ++s) {
            const unsigned* bp = xs + (s * 16 + c) * XSTR + ks * 32 + q * 8;
            split32(*(const uint4*)bp, *(const uint4*)(bp + 4), bhi[s], blo[s]);
        }
#pragma unroll
        for (int m = 0; m < 2; ++m)
#pragma unroll
            for (int s = 0; s < 2; ++s) {
                acc[m][s] = __builtin_amdgcn_mfma_f32_16x16x32_f16(ahi[m], bhi[s], acc[m][s], 0, 0, 0);
                acc[m][s] = __builtin_amdgcn_mfma_f32_16x16x32_f16(ahi[m], blo[s], acc[m][s], 0, 0, 0);
                acc[m][s] = __builtin_amdgcn_mfma_f32_16x16x32_f16(alo[m], bhi[s], acc[m][s], 0, 0, 0);
            }
    }
    unsigned* zw = (unsigned*)x;
#pragma unroll
    for (int m = 0; m < 2; ++m)
#pragma unroll
        for (int s = 0; s < 2; ++s) {
            unsigned* zp = zw + (r0 + s * 16 + c) * 512 + (mt0 + m) * 16 + q * 4;
            uint4 pw;
            pw.x = packhl(acc[m][s][0]); pw.y = packhl(acc[m][s][1]);
            pw.z = packhl(acc[m][s][2]); pw.w = packhl(acc[m][s][3]);
            *(uint4*)zp = pw;
        }
}

// ======================= persistent sequential kernel ======================
__device__ __forceinline__ void grid_barrier(int* bar, int phase) {
    __syncthreads();
    if (threadIdx.x == 0) {
        const int slot = blockIdx.x & 3;
        __hip_atomic_fetch_add(&bar[BSLOT(phase, slot)], 1, __ATOMIC_RELAXED, __HIP_MEMORY_SCOPE_AGENT);
        int s;
        do {
            s = 0;
#pragma unroll
            for (int j = 0; j < 4; ++j)
                s += __hip_atomic_load(&bar[BSLOT(phase, j)], __ATOMIC_RELAXED, __HIP_MEMORY_SCOPE_AGENT);
            if (s < NBB) __builtin_amdgcn_s_sleep(2);
        } while (s < NBB);
    }
    __syncthreads();
    __builtin_amdgcn_fence(__ATOMIC_ACQUIRE, "agent");
}

// BN stats over batch for the block's 16 columns. C/D layout, 16 waves:
// lane (q,c), wave w holds m=q*4+r, n=w*16+c.
__device__ __forceinline__ void bn_stats1(const f32x4 v, float* bnS, float* bnQ,
                                          float* bnM, float* bnR, int q, int c, int w, int tid) {
    float s[4], sq[4];
#pragma unroll
    for (int r = 0; r < 4; ++r) { s[r] = v[r]; sq[r] = v[r] * v[r]; }
#pragma unroll
    for (int mk = 1; mk < 16; mk <<= 1) {
#pragma unroll
        for (int r = 0; r < 4; ++r) {
            s[r]  += __shfl_xor(s[r],  mk, 64);
            sq[r] += __shfl_xor(sq[r], mk, 64);
        }
    }
    if (c == 0) {
#pragma unroll
        for (int r = 0; r < 4; ++r) { bnS[(q*4+r)*16 + w] = s[r]; bnQ[(q*4+r)*16 + w] = sq[r]; }
    }
    __syncthreads();
    if (tid < 16) {
        const float4* pS = (const float4*)(bnS + tid * 16);
        const float4* pQ = (const float4*)(bnQ + tid * 16);
        float4 s0 = pS[0], s1 = pS[1], s2 = pS[2], s3 = pS[3];
        float4 q0 = pQ[0], q1 = pQ[1], q2 = pQ[2], q3 = pQ[3];
        float S = (s0.x + s0.y + s0.z + s0.w) + (s1.x + s1.y + s1.z + s1.w)
                + (s2.x + s2.y + s2.z + s2.w) + (s3.x + s3.y + s3.z + s3.w);
        float Q = (q0.x + q0.y + q0.z + q0.w) + (q1.x + q1.y + q1.z + q1.w)
                + (q2.x + q2.y + q2.z + q2.w) + (q3.x + q3.y + q3.z + q3.w);
        float mn  = S * (1.f/256.f);
        float var = Q * (1.f/256.f) - mn * mn;
        bnM[tid] = mn; bnR[tid] = rsqrtf(var + kEPS);
    }
    __syncthreads();
}

// pp: [0..15]=u, [16..31]=g1, [32..47]=be1, [48..63]=g2, [64..79]=be2
__device__ __forceinline__ void bn_tail1(const f32x4 acc, f32x4& h, const float* pp,
                                         float* bnS, float* bnQ, float* bnM, float* bnR,
                                         int q, int c, int w, int tid) {
    bn_stats1(acc, bnS, bnQ, bnM, bnR, q, c, w, tid);
    f32x4 tmp;
#pragma unroll
    for (int r = 0; r < 4; ++r) {
        int m = q*4 + r;
        float zn = (acc[r] - bnM[m]) * bnR[m] * pp[16+m] + pp[32+m];
        float rl = zn + h[r] * pp[m];
        tmp[r] = rl > 0.f ? rl : 0.f;
    }
    bn_stats1(tmp, bnS, bnQ, bnM, bnR, q, c, w, tid);
#pragma unroll
    for (int r = 0; r < 4; ++r) {
        int m = q*4 + r;
        h[r] = (tmp[r] - bnM[m]) * bnR[m] * pp[48+m] + pp[64+m];
    }
}

// ---- exchange layout: TWO half-planes per slot (hi then lo), same 512KB ----
// hi-plane: [K/8=64 groups][B=256][8 fp16 halves] (16B per group-row), 256KB.
// lo-plane at +256KB. Reader loads half8 DIRECTLY (no v_perm unpack).
#define PL64 32768   // plane stride in 8B units (256KB/8)

// write h rows k=c0+q*4+j (j=0..3), batch b: two 8B stores (hi, lo planes)
__device__ __forceinline__ void store_h1(unsigned* hp, const f32x4 h,
                                         int c0, int q, int c, int w) {
    unsigned long long* hpu = (unsigned long long*)hp;
    const int b = w*16 + c;
    const int g = (c0 >> 3) + (q >> 1);          // k-group
    const long long idx = ((long long)g*256 + b)*2 + (q & 1);
    unsigned short uh[4], ul[4];
#pragma unroll
    for (int j = 0; j < 4; ++j) {
        _Float16 hi = (_Float16)h[j];
        _Float16 lo = (_Float16)(h[j] - (float)hi);
        __builtin_memcpy(&uh[j], &hi, 2);
        __builtin_memcpy(&ul[j], &lo, 2);
    }
    unsigned long long H, L;
    __builtin_memcpy(&H, uh, 8);
    __builtin_memcpy(&L, ul, 8);
    __hip_atomic_store(hpu + idx,        H, __ATOMIC_RELAXED, __HIP_MEMORY_SCOPE_AGENT);
    __hip_atomic_store(hpu + idx + PL64, L, __ATOMIC_RELAXED, __HIP_MEMORY_SCOPE_AGENT);
}

// pure GEMM: acc = hprev @ Wm^T (no LDS sync, no BN) — callable back-to-back
// so consecutive cells' load streams overlap with MFMA (phase-split schedule).
__device__ __forceinline__ f32x4 cell_gemm(const unsigned* __restrict__ hw,
                                           const unsigned short* waHi,
                                           const unsigned short* waLo,
                                           int q, int c, int w) {
    f32x4 acc = {};
    const uint4* ph = (const uint4*)hw + (q*256 + w*16 + c);
    const uint4* pl = ph + 16384;                // +256KB
    uint4 Bh[8], Bl[8];
#pragma unroll
    for (int i = 0; i < 8; ++i) {
        Bh[i] = ph[i*1024];
        Bl[i] = pl[i*1024];
    }
#pragma unroll
    for (int i = 0; i < 8; ++i) {
        half8 bhi, blo;
        __builtin_memcpy(&bhi, &Bh[i], 16);
        __builtin_memcpy(&blo, &Bl[i], 16);
        half8 ahi = *(const half8*)(waHi + i*512);
        half8 alo = *(const half8*)(waLo + i*512);
        acc = __builtin_amdgcn_mfma_f32_16x16x32_f16(ahi, bhi, acc, 0, 0, 0);
        acc = __builtin_amdgcn_mfma_f32_16x16x32_f16(ahi, blo, acc, 0, 0, 0);
        acc = __builtin_amdgcn_mfma_f32_16x16x32_f16(alo, bhi, acc, 0, 0, 0);
        Bh[i] = ph[(i + 8)*1024];
        Bl[i] = pl[(i + 8)*1024];
    }
#pragma unroll
    for (int i = 0; i < 8; ++i) {
        half8 bhi, blo;
        __builtin_memcpy(&bhi, &Bh[i], 16);
        __builtin_memcpy(&blo, &Bl[i], 16);
        half8 ahi = *(const half8*)(waHi + (8 + i)*512);
        half8 alo = *(const half8*)(waLo + (8 + i)*512);
        acc = __builtin_amdgcn_mfma_f32_16x16x32_f16(ahi, bhi, acc, 0, 0, 0);
        acc = __builtin_amdgcn_mfma_f32_16x16x32_f16(ahi, blo, acc, 0, 0, 0);
        acc = __builtin_amdgcn_mfma_f32_16x16x32_f16(alo, bhi, acc, 0, 0, 0);
    }
    return acc;
}

// 3-stage layer pipeline over 96 blocks, SSTEP=8 timesteps per tick.
// Phase-split schedule per tick: (A) all 8 independent GEMMs back-to-back
// (one continuous 4MB load stream, zero syncthreads), then (B) the 8 serial
// BN tails (h-register recurrence + stores). Roles/parity as before:
//   role 0 (blk  0..31): t = 8*tau..+7        -> E0[tau&1][0..7]
//   role 1 (blk 32..63): t = 8*(tau-1)..+7  reads E0[(tau-1)&1][i] -> E1[...][i]
//   role 2 (blk 64..95): t = 8*(tau-2)..+7  reads E1[tau&1][i]   (h2 stays local)
__global__ __launch_bounds__(BT, 4) void indrnn(
    const unsigned* __restrict__ z0,             // packed z0 (in x's buffer)
    const float* __restrict__ Wm,
    const float* __restrict__ u0,  const float* __restrict__ g10,
    const float* __restrict__ be10, const float* __restrict__ g20,
    const float* __restrict__ be20,
    const float* __restrict__ um,  const float* __restrict__ g1m,
    const float* __restrict__ be1m, const float* __restrict__ g2m,
    const float* __restrict__ be2m,
    const float* __restrict__ Wfc, const float* __restrict__ bfc,
    float* __restrict__ out, int* __restrict__ bar,
    unsigned* __restrict__ hpws,                 // E0[2][8],E1[2][8]: 32 x 131072 words
    float* __restrict__ h2n)                     // [256][512] fp32
{
    __shared__ __align__(16) unsigned short WAhi_m[8192];  // Wm A-frags hi (head reuses)
    __shared__ __align__(16) unsigned short WAlo_m[8192];
    __shared__ float bnS[256], bnQ[256], bnM[16], bnR[16];
    __shared__ float prm[160];

    const int tid  = threadIdx.x;
    const int blk  = blockIdx.x;
    const int role = blk >> 5;
    const int cid  = blk & 31;
    const int lane = tid & 63;
    const int w    = tid >> 6;
    const int q    = lane >> 4;
    const int c    = lane & 15;
    const int c0   = cid * 16;

    // ---- stage Wm A-fragments into LDS (GEMM roles only), hi/lo planes ----
    if (role != 0) {
        int e = tid;
        int ks = e >> 6, l = e & 63;
        int cc = l & 15, qq = l >> 4;
        const float* sm = Wm + (size_t)(c0 + cc)*512 + ks*32 + qq*8;
        unsigned short mh[8], ml[8];
#pragma unroll
        for (int j = 0; j < 8; ++j) {
            unsigned pm = packhl(sm[j]);
            mh[j] = (unsigned short)pm; ml[j] = (unsigned short)(pm >> 16);
        }
        __builtin_memcpy(&WAhi_m[e*8], mh, 16);
        __builtin_memcpy(&WAlo_m[e*8], ml, 16);
    }
    if (tid < 16) {
        prm[tid]      = u0[c0+tid];   prm[16+tid]  = g10[c0+tid];  prm[32+tid]  = be10[c0+tid];
        prm[48+tid]   = g20[c0+tid];  prm[64+tid]  = be20[c0+tid];
        prm[80+tid]   = um[c0+tid];   prm[96+tid]  = g1m[c0+tid];  prm[112+tid] = be1m[c0+tid];
        prm[128+tid]  = g2m[c0+tid];  prm[144+tid] = be2m[c0+tid];
    }
    __syncthreads();

    f32x4 h0 = {}, h1 = {}, h2 = {};
    const unsigned short* waHi = WAhi_m + lane*8;
    const unsigned short* waLo = WAlo_m + lane*8;
    unsigned* E0 = hpws;                          // + (par*SSTEP + i)*131072
    unsigned* E1 = hpws + SSTEP*2*131072;

    for (int tau = 0; tau <= NT + 1; ++tau) {
        if (role == 0) {
            if (tau < NT) {
                const int p = tau & 1;
                f32x4 acc[SSTEP];
#pragma unroll
                for (int i = 0; i < SSTEP; ++i) {      // phase A: z0 loads+unpack
                    const int t = tau*SSTEP + i;
                    const unsigned* zp = z0 + (long long)(w*16 + c)*131072LL
                                       + (long long)t*512 + c0 + q*4;
                    uint4 zw = *(const uint4*)zp;
                    acc[i][0] = unpackhl(zw.x); acc[i][1] = unpackhl(zw.y);
                    acc[i][2] = unpackhl(zw.z); acc[i][3] = unpackhl(zw.w);
                }
#pragma unroll
                for (int i = 0; i < SSTEP; ++i) {      // phase B: serial BN chain
                    bn_tail1(acc[i], h0, prm, bnS, bnQ, bnM, bnR, q, c, w, tid);
                    store_h1(E0 + (p*SSTEP + i)*131072, h0, c0, q, c, w);
                }
            }
        } else if (role == 1) {
            if (tau >= 1 && tau <= NT) {
                const int p = (tau - 1) & 1;
                f32x4 acc[SSTEP];
#pragma unroll
                for (int i = 0; i < SSTEP; ++i)        // phase A: 8 independent GEMMs
                    acc[i] = cell_gemm(E0 + (p*SSTEP + i)*131072, waHi, waLo, q, c, w);
#pragma unroll
                for (int i = 0; i < SSTEP; ++i) {      // phase B: serial BN chain
                    bn_tail1(acc[i], h1, prm + 80, bnS, bnQ, bnM, bnR, q, c, w, tid);
                    store_h1(E1 + (p*SSTEP + i)*131072, h1, c0, q, c, w);
                }
            }
        } else {
            if (tau >= 2) {
                const int p = tau & 1;    // (tau-2)&1 == tau&1
                f32x4 acc[SSTEP];
#pragma unroll
                for (int i = 0; i < SSTEP; ++i)
                    acc[i] = cell_gemm(E1 + (p*SSTEP + i)*131072, waHi, waLo, q, c, w);
#pragma unroll
                for (int i = 0; i < SSTEP; ++i)
                    bn_tail1(acc[i], h2, prm + 80, bnS, bnQ, bnM, bnR, q, c, w, tid);
            }
        }
        grid_barrier(bar, tau);
    }

    // ---- final h2 -> h2n (fp32, 8B agent stores), by role 2 ----
    if (role == 2) {
        unsigned long long* h2u = (unsigned long long*)h2n;
        const int b = w*16 + c;
#pragma unroll
        for (int pr = 0; pr < 2; ++pr) {
            float fv[2] = { h2[pr*2], h2[pr*2+1] };
            unsigned long long val;
            __builtin_memcpy(&val, fv, 8);
            __hip_atomic_store(h2u + (((size_t)b*512 + c0 + q*4) >> 1) + pr, val,
                               __ATOMIC_RELAXED, __HIP_MEMORY_SCOPE_AGENT);
        }
    }
    grid_barrier(bar, NT + 2);

    // ---- head: blocks 0..31, 8 batch rows each, logits + log_softmax ----
    if (blk < 32) {
        float* hs = (float*)WAhi_m;   // reuse 16KB LDS: 8 rows x 512 fp32
        __syncthreads();
        ((float4*)hs)[tid] = ((const float4*)(h2n + (size_t)blk*4096))[tid];
        __syncthreads();
        if (w < 8) {
            const int row = w;
            const int o0  = lane * 4;
            const float* hrow = hs + row*512;
            float dots[4] = {bfc[o0], bfc[o0+1], bfc[o0+2], bfc[o0+3]};
#pragma unroll 4
            for (int h = 0; h < 512; h += 4) {
                float4 hv = *(const float4*)(hrow + h);
#pragma unroll
                for (int oo = 0; oo < 4; ++oo) {
                    float4 wv = *(const float4*)(Wfc + (size_t)(o0+oo)*512 + h);
                    dots[oo] += hv.x*wv.x + hv.y*wv.y + hv.z*wv.z + hv.w*wv.w;
                }
            }
            float M = fmaxf(fmaxf(dots[0], dots[1]), fmaxf(dots[2], dots[3]));
#pragma unroll
            for (int mk = 1; mk < 64; mk <<= 1) M = fmaxf(M, __shfl_xor(M, mk, 64));
            float S = 0.f;
#pragma unroll
            for (int oo = 0; oo < 4; ++oo) S += expf(dots[oo] - M);
#pragma unroll
            for (int mk = 1; mk < 64; mk <<= 1) S += __shfl_xor(S, mk, 64);
            float lse = M + logf(S);
#pragma unroll
            for (int oo = 0; oo < 4; ++oo)
                out[(size_t)(blk*8 + row)*256 + o0 + oo] = dots[oo] - lse;
        }
    }
}

extern "C" void kernel_launch(void* const* d_in, const int* in_sizes, int n_in,
                              void* d_out, int out_size, void* d_ws, size_t ws_size,
                              hipStream_t stream) {
    float* x          = (float*)d_in[0];          // mutated; harness restores pristine
    const float* W0   = (const float*)d_in[1];
    const float* u0   = (const float*)d_in[3];
    const float* g10  = (const float*)d_in[4];
    const float* be10 = (const float*)d_in[5];
    const float* g20  = (const float*)d_in[6];
    const float* be20 = (const float*)d_in[7];
    const float* Wm   = (const float*)d_in[8];
    const float* um   = (const float*)d_in[10];
    const float* g1m  = (const float*)d_in[11];
    const float* be1m = (const float*)d_in[12];
    const float* g2m  = (const float*)d_in[13];
    const float* be2m = (const float*)d_in[14];
    const float* Wfc  = (const float*)d_in[15];
    const float* bfc  = (const float*)d_in[16];
    // b0 (d_in[2]) / bm (d_in[9]) cancel inside training-mode BatchNorm -> unused
    float* out = (float*)d_out;

    char* ws = (char*)d_ws;
    int* bar        = (int*)ws;                              // 128KB barrier phases
    unsigned* hpws  = (unsigned*)(ws + 131072);              // 32 x 512KB h exchange (16MB)
    float* h2n      = (float*)(ws + 131072 + 16777216);      // 512KB
    unsigned* W0p   = (unsigned*)(ws + 131072 + 17301504);   // 1MB packed W0

    hipMemsetAsync(bar, 0, BARBYTES, stream);
    hipLaunchKernelGGL(w0pack, dim3(256), dim3(256), 0, stream, W0, W0p);
    hipLaunchKernelGGL(zgemm, dim3(2048), dim3(1024), 0, stream, x, W0p);
    hipLaunchKernelGGL(indrnn, dim3(NBB), dim3(BT), 0, stream,
                       (const unsigned*)x, Wm, u0, g10, be10, g20, be20,
                       um, g1m, be1m, g2m, be2m, Wfc, bfc,
                       out, bar, hpws, h2n);
}

// Round 9
// 3140.791 us; speedup vs baseline: 1.1539x; 1.1539x over previous
//
#include <hip/hip_runtime.h>
#include <math.h>

// Problem: B=256, T=256, D=H=512, O=256, L=3 (cell0 + 2 shared middle cells)
#define kT 256
#define kEPS 1e-5f
#define NBB 96     // 3 groups x 32 persistent blocks (cell0 | cell1 | cell2)
#define BT 1024    // 16 waves; launch_bounds min-blocks=1 -> VGPR cap 128 (was 4 -> cap 64, caused spills/shallow pipelines)
#define SSTEP 8    // timesteps per grid-barrier tick (amortize ~14us barrier cost)
#define NT (kT / SSTEP)   // 32 ticks of work

typedef __attribute__((ext_vector_type(8))) _Float16 half8;  // 8 fp16 (4 VGPRs)
typedef __attribute__((ext_vector_type(4))) float f32x4;

// barrier: 4 spread counters per phase, 64B apart; phase-indexed (memset at launch)
#define BSLOT(p, j) (((p)*4 + (j)) * 16)
#define BARBYTES (260 * 4 * 64)

// pack v as {hi=fp16(v)} | {lo=fp16(v-hi)}<<16 : 22-bit effective mantissa in 4B
__device__ __forceinline__ unsigned packhl(float f) {
    _Float16 hi = (_Float16)f;
    _Float16 lo = (_Float16)(f - (float)hi);
    unsigned short uh, ul;
    __builtin_memcpy(&uh, &hi, 2);
    __builtin_memcpy(&ul, &lo, 2);
    return (unsigned)uh | ((unsigned)ul << 16);
}

__device__ __forceinline__ float unpackhl(unsigned wd) {
    unsigned short uh = (unsigned short)wd, ul = (unsigned short)(wd >> 16);
    _Float16 hi, lo;
    __builtin_memcpy(&hi, &uh, 2);
    __builtin_memcpy(&lo, &ul, 2);
    return (float)hi + (float)lo;
}

// split 8 packed words (two uint4) into hi/lo half8 fragments (8 v_perm_b32)
__device__ __forceinline__ void split32(uint4 A, uint4 B, half8& hi, half8& lo) {
    unsigned hh[4], ll[4];
    hh[0] = __builtin_amdgcn_perm(A.y, A.x, 0x05040100u);
    ll[0] = __builtin_amdgcn_perm(A.y, A.x, 0x07060302u);
    hh[1] = __builtin_amdgcn_perm(A.w, A.z, 0x05040100u);
    ll[1] = __builtin_amdgcn_perm(A.w, A.z, 0x07060302u);
    hh[2] = __builtin_amdgcn_perm(B.y, B.x, 0x05040100u);
    ll[2] = __builtin_amdgcn_perm(B.y, B.x, 0x07060302u);
    hh[3] = __builtin_amdgcn_perm(B.w, B.z, 0x05040100u);
    ll[3] = __builtin_amdgcn_perm(B.w, B.z, 0x07060302u);
    __builtin_memcpy(&hi, hh, 16);
    __builtin_memcpy(&lo, ll, 16);
}

// ============================ kernel 1: pack W0 ============================
__global__ __launch_bounds__(256) void w0pack(const float* __restrict__ W0,
                                              unsigned* __restrict__ W0p) {
    const int i4 = (blockIdx.x * 256 + threadIdx.x) * 4;   // 262144 words total
    float4 v = *(const float4*)(W0 + i4);
    uint4 pw;
    pw.x = packhl(v.x); pw.y = packhl(v.y); pw.z = packhl(v.z); pw.w = packhl(v.w);
    *(uint4*)(W0p + i4) = pw;
}

// ================= kernel 2: z0 = x @ W0^T, packed, IN PLACE over x ========
#define ZROWS 32
#define XSTR 516   // padded word stride: 2-way bank aliasing only (free)
__global__ __launch_bounds__(1024, 4) void zgemm(float* __restrict__ x,
                                                 const unsigned* __restrict__ W0p) {
    __shared__ unsigned xs[ZROWS * XSTR];
    const int tid = threadIdx.x;
    const long long r0 = (long long)blockIdx.x * ZROWS;

    {   // stage 32 rows x 512 floats -> packed words in LDS
        const int row = tid >> 5;
        const int k0 = (tid & 31) * 16;
        const float* src = x + (r0 + row) * 512 + k0;
        unsigned* dst = xs + row * XSTR + k0;
#pragma unroll
        for (int i = 0; i < 4; ++i) {
            float4 v = *(const float4*)(src + i * 4);
            uint4 pw;
            pw.x = packhl(v.x); pw.y = packhl(v.y); pw.z = packhl(v.z); pw.w = packhl(v.w);
            *(uint4*)(dst + i * 4) = pw;
        }
    }
    __syncthreads();

    const int w = tid >> 6, lane = tid & 63, q = lane >> 4, c = lane & 15;
    const int mt0 = w * 2;
    f32x4 acc[2][2] = {};
#pragma unroll
    for (int ks = 0; ks < 16; ++ks) {
        half8 ahi[2], alo[2], bhi[2], blo[2];
#pragma unroll
        for (int m = 0; m < 2; ++m) {
            const unsigned* ap = W0p + ((mt0 + m) * 16 + c) * 512 + ks * 32 + q * 8;
            split32(*(const uint4*)ap, *(const uint4*)(ap + 4), ahi[m], alo[m]);
        }
#pragma unroll
        for (int s = 0; s < 2; ++s) {
            const unsigned* bp = xs + (s * 16 + c) * XSTR + ks * 32 + q * 8;
            split32(*(const uint4*)bp, *(const uint4*)(bp + 4), bhi[s], blo[s]);
        }
#pragma unroll
        for (int m = 0; m < 2; ++m)
#pragma unroll
            for (int s = 0; s < 2; ++s) {
                acc[m][s] = __builtin_amdgcn_mfma_f32_16x16x32_f16(ahi[m], bhi[s], acc[m][s], 0, 0, 0);
                acc[m][s] = __builtin_amdgcn_mfma_f32_16x16x32_f16(ahi[m], blo[s], acc[m][s], 0, 0, 0);
                acc[m][s] = __builtin_amdgcn_mfma_f32_16x16x32_f16(alo[m], bhi[s], acc[m][s], 0, 0, 0);
            }
    }
    unsigned* zw = (unsigned*)x;
#pragma unroll
    for (int m = 0; m < 2; ++m)
#pragma unroll
        for (int s = 0; s < 2; ++s) {
            unsigned* zp = zw + (r0 + s * 16 + c) * 512 + (mt0 + m) * 16 + q * 4;
            uint4 pw;
            pw.x = packhl(acc[m][s][0]); pw.y = packhl(acc[m][s][1]);
            pw.z = packhl(acc[m][s][2]); pw.w = packhl(acc[m][s][3]);
            *(uint4*)zp = pw;
        }
}

// ======================= persistent sequential kernel ======================
__device__ __forceinline__ void grid_barrier(int* bar, int phase) {
    __syncthreads();
    if (threadIdx.x == 0) {
        const int slot = blockIdx.x & 3;
        __hip_atomic_fetch_add(&bar[BSLOT(phase, slot)], 1, __ATOMIC_RELAXED, __HIP_MEMORY_SCOPE_AGENT);
        int s;
        do {
            s = 0;
#pragma unroll
            for (int j = 0; j < 4; ++j)
                s += __hip_atomic_load(&bar[BSLOT(phase, j)], __ATOMIC_RELAXED, __HIP_MEMORY_SCOPE_AGENT);
            if (s < NBB) __builtin_amdgcn_s_sleep(2);
        } while (s < NBB);
    }
    __syncthreads();
    __builtin_amdgcn_fence(__ATOMIC_ACQUIRE, "agent");
}

// BN stats over batch for the block's 16 columns. C/D layout, 16 waves:
// lane (q,c), wave w holds m=q*4+r, n=w*16+c.
__device__ __forceinline__ void bn_stats1(const f32x4 v, float* bnS, float* bnQ,
                                          float* bnM, float* bnR, int q, int c, int w, int tid) {
    float s[4], sq[4];
#pragma unroll
    for (int r = 0; r < 4; ++r) { s[r] = v[r]; sq[r] = v[r] * v[r]; }
#pragma unroll
    for (int mk = 1; mk < 16; mk <<= 1) {
#pragma unroll
        for (int r = 0; r < 4; ++r) {
            s[r]  += __shfl_xor(s[r],  mk, 64);
            sq[r] += __shfl_xor(sq[r], mk, 64);
        }
    }
    if (c == 0) {
#pragma unroll
        for (int r = 0; r < 4; ++r) { bnS[(q*4+r)*16 + w] = s[r]; bnQ[(q*4+r)*16 + w] = sq[r]; }
    }
    __syncthreads();
    if (tid < 16) {
        const float4* pS = (const float4*)(bnS + tid * 16);
        const float4* pQ = (const float4*)(bnQ + tid * 16);
        float4 s0 = pS[0], s1 = pS[1], s2 = pS[2], s3 = pS[3];
        float4 q0 = pQ[0], q1 = pQ[1], q2 = pQ[2], q3 = pQ[3];
        float S = (s0.x + s0.y + s0.z + s0.w) + (s1.x + s1.y + s1.z + s1.w)
                + (s2.x + s2.y + s2.z + s2.w) + (s3.x + s3.y + s3.z + s3.w);
        float Q = (q0.x + q0.y + q0.z + q0.w) + (q1.x + q1.y + q1.z + q1.w)
                + (q2.x + q2.y + q2.z + q2.w) + (q3.x + q3.y + q3.z + q3.w);
        float mn  = S * (1.f/256.f);
        float var = Q * (1.f/256.f) - mn * mn;
        bnM[tid] = mn; bnR[tid] = rsqrtf(var + kEPS);
    }
    __syncthreads();
}

// pp: [0..15]=u, [16..31]=g1, [32..47]=be1, [48..63]=g2, [64..79]=be2
__device__ __forceinline__ void bn_tail1(const f32x4 acc, f32x4& h, const float* pp,
                                         float* bnS, float* bnQ, float* bnM, float* bnR,
                                         int q, int c, int w, int tid) {
    bn_stats1(acc, bnS, bnQ, bnM, bnR, q, c, w, tid);
    f32x4 tmp;
#pragma unroll
    for (int r = 0; r < 4; ++r) {
        int m = q*4 + r;
        float zn = (acc[r] - bnM[m]) * bnR[m] * pp[16+m] + pp[32+m];
        float rl = zn + h[r] * pp[m];
        tmp[r] = rl > 0.f ? rl : 0.f;
    }
    bn_stats1(tmp, bnS, bnQ, bnM, bnR, q, c, w, tid);
#pragma unroll
    for (int r = 0; r < 4; ++r) {
        int m = q*4 + r;
        h[r] = (tmp[r] - bnM[m]) * bnR[m] * pp[48+m] + pp[64+m];
    }
}

// ---- exchange layout: TWO half-planes per slot (hi then lo), same 512KB ----
// hi-plane: [K/8=64 groups][B=256][8 fp16 halves] (16B per group-row), 256KB.
// lo-plane at +256KB. Reader loads half8 DIRECTLY (no v_perm unpack).
#define PL64 32768   // plane stride in 8B units (256KB/8)

// write h rows k=c0+q*4+j (j=0..3), batch b: two 8B stores (hi, lo planes)
__device__ __forceinline__ void store_h1(unsigned* hp, const f32x4 h,
                                         int c0, int q, int c, int w) {
    unsigned long long* hpu = (unsigned long long*)hp;
    const int b = w*16 + c;
    const int g = (c0 >> 3) + (q >> 1);          // k-group
    const long long idx = ((long long)g*256 + b)*2 + (q & 1);
    unsigned short uh[4], ul[4];
#pragma unroll
    for (int j = 0; j < 4; ++j) {
        _Float16 hi = (_Float16)h[j];
        _Float16 lo = (_Float16)(h[j] - (float)hi);
        __builtin_memcpy(&uh[j], &hi, 2);
        __builtin_memcpy(&ul[j], &lo, 2);
    }
    unsigned long long H, L;
    __builtin_memcpy(&H, uh, 8);
    __builtin_memcpy(&L, ul, 8);
    __hip_atomic_store(hpu + idx,        H, __ATOMIC_RELAXED, __HIP_MEMORY_SCOPE_AGENT);
    __hip_atomic_store(hpu + idx + PL64, L, __ATOMIC_RELAXED, __HIP_MEMORY_SCOPE_AGENT);
}

// GEMM cell: z = hprev @ Wm^T from plane-split exchange. 8-deep rotating load
// pipeline; B-fragments load directly as half8 (zero unpack VALU).
__device__ __forceinline__ void cell_h1(const unsigned* __restrict__ hw,
                                        const unsigned short* waHi, const unsigned short* waLo,
                                        f32x4& h, const float* pp,
                                        float* bnS, float* bnQ, float* bnM, float* bnR,
                                        unsigned* hpdst, int c0, int q, int c, int w, int tid) {
    f32x4 acc = {};
    // thread reads k-groups g = 4i+q, batch b: hi at uint4 index g*256+b
    const uint4* ph = (const uint4*)hw + (q*256 + w*16 + c);
    const uint4* pl = ph + 16384;                // +256KB
    uint4 Bh[8], Bl[8];
#pragma unroll
    for (int i = 0; i < 8; ++i) {
        Bh[i] = ph[i*1024];
        Bl[i] = pl[i*1024];
    }
#pragma unroll
    for (int i = 0; i < 8; ++i) {
        half8 bhi, blo;
        __builtin_memcpy(&bhi, &Bh[i], 16);
        __builtin_memcpy(&blo, &Bl[i], 16);
        half8 ahi = *(const half8*)(waHi + i*512);
        half8 alo = *(const half8*)(waLo + i*512);
        acc = __builtin_amdgcn_mfma_f32_16x16x32_f16(ahi, bhi, acc, 0, 0, 0);
        acc = __builtin_amdgcn_mfma_f32_16x16x32_f16(ahi, blo, acc, 0, 0, 0);
        acc = __builtin_amdgcn_mfma_f32_16x16x32_f16(alo, bhi, acc, 0, 0, 0);
        Bh[i] = ph[(i + 8)*1024];
        Bl[i] = pl[(i + 8)*1024];
    }
#pragma unroll
    for (int i = 0; i < 8; ++i) {
        half8 bhi, blo;
        __builtin_memcpy(&bhi, &Bh[i], 16);
        __builtin_memcpy(&blo, &Bl[i], 16);
        half8 ahi = *(const half8*)(waHi + (8 + i)*512);
        half8 alo = *(const half8*)(waLo + (8 + i)*512);
        acc = __builtin_amdgcn_mfma_f32_16x16x32_f16(ahi, bhi, acc, 0, 0, 0);
        acc = __builtin_amdgcn_mfma_f32_16x16x32_f16(ahi, blo, acc, 0, 0, 0);
        acc = __builtin_amdgcn_mfma_f32_16x16x32_f16(alo, bhi, acc, 0, 0, 0);
    }
    bn_tail1(acc, h, pp, bnS, bnQ, bnM, bnR, q, c, w, tid);
    if (hpdst) store_h1(hpdst, h, c0, q, c, w);
}

// cell0-lite: z0 precomputed -> one 16B load + unpack + BN tail
__device__ __forceinline__ void cell0lite(const unsigned* __restrict__ z0, int t,
                                          f32x4& h0, const float* pp,
                                          float* bnS, float* bnQ, float* bnM, float* bnR,
                                          unsigned* hpdst, int c0, int q, int c, int w, int tid) {
    const unsigned* zp = z0 + (long long)(w*16 + c)*131072LL + (long long)t*512 + c0 + q*4;
    uint4 zw = *(const uint4*)zp;
    f32x4 acc;
    acc[0] = unpackhl(zw.x); acc[1] = unpackhl(zw.y);
    acc[2] = unpackhl(zw.z); acc[3] = unpackhl(zw.w);
    bn_tail1(acc, h0, pp, bnS, bnQ, bnM, bnR, q, c, w, tid);
    store_h1(hpdst, h0, c0, q, c, w);
}

// 3-stage layer pipeline over 96 blocks, SSTEP=8 timesteps per tick:
//   role 0 (blk  0..31): t = 8*tau..8*tau+7       -> E0[tau&1][0..7]
//   role 1 (blk 32..63): t = 8*(tau-1)..+7  reads E0[(tau-1)&1][i] -> E1[(tau-1)&1][i]
//   role 2 (blk 64..95): t = 8*(tau-2)..+7  reads E1[tau&1][i]     (h2 stays local)
// One grid barrier per tick (34 total); every cross-group read targets data
// written one full barrier earlier (double-buffered by tick parity).
__global__ __launch_bounds__(BT, 1) void indrnn(
    const unsigned* __restrict__ z0,             // packed z0 (in x's buffer)
    const float* __restrict__ Wm,
    const float* __restrict__ u0,  const float* __restrict__ g10,
    const float* __restrict__ be10, const float* __restrict__ g20,
    const float* __restrict__ be20,
    const float* __restrict__ um,  const float* __restrict__ g1m,
    const float* __restrict__ be1m, const float* __restrict__ g2m,
    const float* __restrict__ be2m,
    const float* __restrict__ Wfc, const float* __restrict__ bfc,
    float* __restrict__ out, int* __restrict__ bar,
    unsigned* __restrict__ hpws,                 // E0[2][8],E1[2][8]: 32 x 131072 words
    float* __restrict__ h2n)                     // [256][512] fp32
{
    __shared__ __align__(16) unsigned short WAhi_m[8192];  // Wm A-frags hi (head reuses)
    __shared__ __align__(16) unsigned short WAlo_m[8192];
    __shared__ float bnS[256], bnQ[256], bnM[16], bnR[16];
    __shared__ float prm[160];

    const int tid  = threadIdx.x;
    const int blk  = blockIdx.x;
    const int role = blk >> 5;
    const int cid  = blk & 31;
    const int lane = tid & 63;
    const int w    = tid >> 6;
    const int q    = lane >> 4;
    const int c    = lane & 15;
    const int c0   = cid * 16;

    // ---- stage Wm A-fragments into LDS (GEMM roles only), hi/lo planes ----
    if (role != 0) {
        int e = tid;
        int ks = e >> 6, l = e & 63;
        int cc = l & 15, qq = l >> 4;
        const float* sm = Wm + (size_t)(c0 + cc)*512 + ks*32 + qq*8;
        unsigned short mh[8], ml[8];
#pragma unroll
        for (int j = 0; j < 8; ++j) {
            unsigned pm = packhl(sm[j]);
            mh[j] = (unsigned short)pm; ml[j] = (unsigned short)(pm >> 16);
        }
        __builtin_memcpy(&WAhi_m[e*8], mh, 16);
        __builtin_memcpy(&WAlo_m[e*8], ml, 16);
    }
    if (tid < 16) {
        prm[tid]      = u0[c0+tid];   prm[16+tid]  = g10[c0+tid];  prm[32+tid]  = be10[c0+tid];
        prm[48+tid]   = g20[c0+tid];  prm[64+tid]  = be20[c0+tid];
        prm[80+tid]   = um[c0+tid];   prm[96+tid]  = g1m[c0+tid];  prm[112+tid] = be1m[c0+tid];
        prm[128+tid]  = g2m[c0+tid];  prm[144+tid] = be2m[c0+tid];
    }
    __syncthreads();

    f32x4 h0 = {}, h1 = {}, h2 = {};
    const unsigned short* waHi = WAhi_m + lane*8;
    const unsigned short* waLo = WAlo_m + lane*8;
    unsigned* E0 = hpws;                          // + (par*SSTEP + i)*131072
    unsigned* E1 = hpws + SSTEP*2*131072;

    for (int tau = 0; tau <= NT + 1; ++tau) {
        if (role == 0) {
            if (tau < NT) {
                const int p = tau & 1;
                for (int i = 0; i < SSTEP; ++i)
                    cell0lite(z0, tau*SSTEP + i, h0, prm, bnS, bnQ, bnM, bnR,
                              E0 + (p*SSTEP + i)*131072, c0, q, c, w, tid);
            }
        } else if (role == 1) {
            if (tau >= 1 && tau <= NT) {
                const int p = (tau - 1) & 1;
                for (int i = 0; i < SSTEP; ++i)
                    cell_h1(E0 + (p*SSTEP + i)*131072, waHi, waLo, h1, prm + 80,
                            bnS, bnQ, bnM, bnR, E1 + (p*SSTEP + i)*131072,
                            c0, q, c, w, tid);
            }
        } else {
            if (tau >= 2) {
                const int p = tau & 1;    // (tau-2)&1 == tau&1
                for (int i = 0; i < SSTEP; ++i)
                    cell_h1(E1 + (p*SSTEP + i)*131072, waHi, waLo, h2, prm + 80,
                            bnS, bnQ, bnM, bnR, (unsigned*)nullptr, c0, q, c, w, tid);
            }
        }
        grid_barrier(bar, tau);
    }

    // ---- final h2 -> h2n (fp32, 8B agent stores), by role 2 ----
    if (role == 2) {
        unsigned long long* h2u = (unsigned long long*)h2n;
        const int b = w*16 + c;
#pragma unroll
        for (int pr = 0; pr < 2; ++pr) {
            float fv[2] = { h2[pr*2], h2[pr*2+1] };
            unsigned long long val;
            __builtin_memcpy(&val, fv, 8);
            __hip_atomic_store(h2u + (((size_t)b*512 + c0 + q*4) >> 1) + pr, val,
                               __ATOMIC_RELAXED, __HIP_MEMORY_SCOPE_AGENT);
        }
    }
    grid_barrier(bar, NT + 2);

    // ---- head: blocks 0..31, 8 batch rows each, logits + log_softmax ----
    if (blk < 32) {
        float* hs = (float*)WAhi_m;   // reuse 16KB LDS: 8 rows x 512 fp32
        __syncthreads();
        ((float4*)hs)[tid] = ((const float4*)(h2n + (size_t)blk*4096))[tid];
        __syncthreads();
        if (w < 8) {
            const int row = w;
            const int o0  = lane * 4;
            const float* hrow = hs + row*512;
            float dots[4] = {bfc[o0], bfc[o0+1], bfc[o0+2], bfc[o0+3]};
#pragma unroll 4
            for (int h = 0; h < 512; h += 4) {
                float4 hv = *(const float4*)(hrow + h);
#pragma unroll
                for (int oo = 0; oo < 4; ++oo) {
                    float4 wv = *(const float4*)(Wfc + (size_t)(o0+oo)*512 + h);
                    dots[oo] += hv.x*wv.x + hv.y*wv.y + hv.z*wv.z + hv.w*wv.w;
                }
            }
            float M = fmaxf(fmaxf(dots[0], dots[1]), fmaxf(dots[2], dots[3]));
#pragma unroll
            for (int mk = 1; mk < 64; mk <<= 1) M = fmaxf(M, __shfl_xor(M, mk, 64));
            float S = 0.f;
#pragma unroll
            for (int oo = 0; oo < 4; ++oo) S += expf(dots[oo] - M);
#pragma unroll
            for (int mk = 1; mk < 64; mk <<= 1) S += __shfl_xor(S, mk, 64);
            float lse = M + logf(S);
#pragma unroll
            for (int oo = 0; oo < 4; ++oo)
                out[(size_t)(blk*8 + row)*256 + o0 + oo] = dots[oo] - lse;
        }
    }
}

extern "C" void kernel_launch(void* const* d_in, const int* in_sizes, int n_in,
                              void* d_out, int out_size, void* d_ws, size_t ws_size,
                              hipStream_t stream) {
    float* x          = (float*)d_in[0];          // mutated; harness restores pristine
    const float* W0   = (const float*)d_in[1];
    const float* u0   = (const float*)d_in[3];
    const float* g10  = (const float*)d_in[4];
    const float* be10 = (const float*)d_in[5];
    const float* g20  = (const float*)d_in[6];
    const float* be20 = (const float*)d_in[7];
    const float* Wm   = (const float*)d_in[8];
    const float* um   = (const float*)d_in[10];
    const float* g1m  = (const float*)d_in[11];
    const float* be1m = (const float*)d_in[12];
    const float* g2m  = (const float*)d_in[13];
    const float* be2m = (const float*)d_in[14];
    const float* Wfc  = (const float*)d_in[15];
    const float* bfc  = (const float*)d_in[16];
    // b0 (d_in[2]) / bm (d_in[9]) cancel inside training-mode BatchNorm -> unused
    float* out = (float*)d_out;

    char* ws = (char*)d_ws;
    int* bar        = (int*)ws;                              // 128KB barrier phases
    unsigned* hpws  = (unsigned*)(ws + 131072);              // 32 x 512KB h exchange (16MB)
    float* h2n      = (float*)(ws + 131072 + 16777216);      // 512KB
    unsigned* W0p   = (unsigned*)(ws + 131072 + 17301504);   // 1MB packed W0

    hipMemsetAsync(bar, 0, BARBYTES, stream);
    hipLaunchKernelGGL(w0pack, dim3(256), dim3(256), 0, stream, W0, W0p);
    hipLaunchKernelGGL(zgemm, dim3(2048), dim3(1024), 0, stream, x, W0p);
    hipLaunchKernelGGL(indrnn, dim3(NBB), dim3(BT), 0, stream,
                       (const unsigned*)x, Wm, u0, g10, be10, g20, be20,
                       um, g1m, be1m, g2m, be2m, Wfc, bfc,
                       out, bar, hpws, h2n);
}